// Round 5
// baseline (90.741 us; speedup 1.0000x reference)
//
#include <hip/hip_runtime.h>
#include <hip/hip_bf16.h>

// x: [4, 4096, 4096] f32, W1: [48, 4096] f32, W2: [48, 48] f32
// out: [4, 4, 4096, 12] f32  (C, B, T, L/C)
#define DDIM 4096
#define LTOT 48
#define RSTRIDE 1040   // 1024 + 16B pad: conflict-free ds_read, contiguous DMA dest

typedef __attribute__((ext_vector_type(4))) float f32x4;
typedef __attribute__((ext_vector_type(8))) short bf16x8;

__device__ __forceinline__ void gload_lds16(const void* g, void* l) {
    __builtin_amdgcn_global_load_lds(
        (const __attribute__((address_space(1))) void*)g,
        (__attribute__((address_space(3))) void*)l, 16, 0, 0);
}

__device__ __forceinline__ unsigned cvt_pk(float x, float y) {
    union { __hip_bfloat162 h; unsigned u; } c;
    c.h = __float22bfloat162_rn(make_float2(x, y));
    return c.u;
}

// ---- kernel 0: W1 fp32 -> bf16 (RNE) into workspace ----
__global__ void w1cvt_kernel(const float* __restrict__ w1, ushort* __restrict__ w1b) {
    int i = blockIdx.x * 256 + threadIdx.x;
    union { float f; unsigned u; } v; v.f = w1[i];
    unsigned r = v.u + 0x7fffu + ((v.u >> 16) & 1u);
    w1b[i] = (ushort)(r >> 16);
}

// ---- fused: 64-row blocks, 4 phase-locked waves, linear padded staging ----
__global__ __launch_bounds__(256, 1) void fused_kernel(
        const float* __restrict__ x,
        const ushort* __restrict__ w1b,
        const float* __restrict__ w2,
        float* __restrict__ out) {
    // 2 buffers x 64 rows x 1040B = 133120 B
    __shared__ __align__(16) char smem[2 * 64 * RSTRIDE];

    const int tid  = threadIdx.x;
    const int wave = tid >> 6;
    const int lane = tid & 63;
    const int rl   = lane & 15;   // A-row / B-row / C-col
    const int kg   = lane >> 4;   // k-group 0..3
    const int row0 = blockIdx.x * 64;
    const int wrow = wave * 16;   // wave's first row within block

    // stage chunk c (K range c*256..+255) of this wave's 16 rows; linear src,
    // contiguous 1KB dest per instruction at padded row stride.
    auto stage = [&](int c) {
        char* lb = smem + (c & 1) * (64 * RSTRIDE);
        const float* xb = x + (size_t)(row0 + wrow) * DDIM + c * 256 + lane * 4;
        #pragma unroll
        for (int r = 0; r < 16; ++r)
            gload_lds16(xb + (size_t)r * DDIM, lb + (wrow + r) * RSTRIDE);
    };

    // B fragments for MFMA step s (K=64): 6 x 16B from L2/L1-resident W1b
    auto loadB = [&](int s, bf16x8 (&bf)[6]) {
        const ushort* bp = w1b + (size_t)rl * DDIM + s * 64 + kg * 8;
        #pragma unroll
        for (int n = 0; n < 3; ++n)
            #pragma unroll
            for (int h = 0; h < 2; ++h)
                bf[n * 2 + h] = *(const bf16x8*)(bp + n * 16 * DDIM + h * 32);
    };

    bf16x8 breg[2][6];
    f32x4 acc[3] = {{0.f,0.f,0.f,0.f},{0.f,0.f,0.f,0.f},{0.f,0.f,0.f,0.f}};
    float ss = 0.f;

    loadB(0, breg[0]);
    stage(0);

    #pragma unroll 1
    for (int c = 0; c < 16; ++c) {
        __builtin_amdgcn_s_barrier();   // phase-lock waves (raw: no vmcnt drain)
        // stage(c) complete: newer vmem = the 24 B-loads of the previous body
        if (c == 0) asm volatile("s_waitcnt vmcnt(0)" ::: "memory");
        else        asm volatile("s_waitcnt vmcnt(24)" ::: "memory");

        const char* lb = smem + (c & 1) * (64 * RSTRIDE) + (wrow + rl) * RSTRIDE;
        f32x4 a[4][2][2];
        #pragma unroll
        for (int t = 0; t < 4; ++t)
            #pragma unroll
            for (int h = 0; h < 2; ++h)
                #pragma unroll
                for (int p = 0; p < 2; ++p)
                    a[t][h][p] = *(const f32x4*)(lb + t * 256 + h * 128 + kg * 32 + p * 16);
        // a[] ready; orders these ds_reads before next stage's DMA writes
        asm volatile("s_waitcnt lgkmcnt(0)" ::: "memory");
        __builtin_amdgcn_sched_barrier(0);
        if (c < 15) stage(c + 1);
        __builtin_amdgcn_sched_barrier(0);
        asm volatile("" ::: "memory");

        #pragma unroll
        for (int t = 0; t < 4; ++t) {
            const int s = c * 4 + t;
            if (s + 1 < 64) loadB(s + 1, breg[(s + 1) & 1]);
            #pragma unroll
            for (int h = 0; h < 2; ++h) {
                f32x4 a0 = a[t][h][0], a1 = a[t][h][1];
                ss = fmaf(a0.x, a0.x, ss); ss = fmaf(a0.y, a0.y, ss);
                ss = fmaf(a0.z, a0.z, ss); ss = fmaf(a0.w, a0.w, ss);
                ss = fmaf(a1.x, a1.x, ss); ss = fmaf(a1.y, a1.y, ss);
                ss = fmaf(a1.z, a1.z, ss); ss = fmaf(a1.w, a1.w, ss);
                union { bf16x8 v; unsigned u[4]; } af;
                af.u[0] = cvt_pk(a0.x, a0.y); af.u[1] = cvt_pk(a0.z, a0.w);
                af.u[2] = cvt_pk(a1.x, a1.y); af.u[3] = cvt_pk(a1.z, a1.w);
                #pragma unroll
                for (int n = 0; n < 3; ++n)
                    acc[n] = __builtin_amdgcn_mfma_f32_16x16x32_bf16(
                                 af.v, breg[s & 1][n * 2 + h], acc[n], 0, 0, 0);
            }
        }
    }

    asm volatile("s_waitcnt vmcnt(0) lgkmcnt(0)" ::: "memory");

    // ---- epilogue ----
    ss += __shfl_xor(ss, 16);
    ss += __shfl_xor(ss, 32);
    const float scl = rsqrtf(ss * (1.0f / (float)DDIM) + 1e-5f);  // row (wrow+rl)

    __syncthreads();   // all waves done with staging LDS -> safe to overlay

    float* dots = (float*)(smem) + wave * (16 * 48);          // per-wave [16][48]
    float* gbuf = (float*)(smem) + 4 * (16 * 48) + wave * (16 * 48);
    float* w2s  = (float*)(smem) + 8 * (16 * 48);             // [48][48] shared

    #pragma unroll
    for (int n = 0; n < 3; ++n)
        #pragma unroll
        for (int i = 0; i < 4; ++i)
            dots[(kg * 4 + i) * 48 + n * 16 + rl] = acc[n][i];

    for (int i = tid; i < LTOT * LTOT; i += 256) w2s[i] = w2[i];
    __syncthreads();

    // gelu for row rl, cols kg*12..+11 (within this wave's tile)
    #pragma unroll
    for (int j = 0; j < 12; ++j) {
        float h = dots[rl * 48 + kg * 12 + j] * scl;
        gbuf[rl * 48 + kg * 12 + j] = h * 0.5f * (1.0f + erff(h * 0.70710678118654752f));
    }
    asm volatile("s_waitcnt lgkmcnt(0)" ::: "memory");
    __builtin_amdgcn_wave_barrier();

    f32x4 grow[12];
    #pragma unroll
    for (int q = 0; q < 12; ++q)
        grow[q] = *(const f32x4*)(gbuf + rl * 48 + q * 4);

    float o[12];
    #pragma unroll
    for (int jj = 0; jj < 12; ++jj) {
        const int l = kg * 12 + jj;
        float sacc = 0.f;
        #pragma unroll
        for (int q = 0; q < 12; ++q) {
            f32x4 wv = *(const f32x4*)(w2s + l * 48 + q * 4);
            sacc = fmaf(grow[q].x, wv.x, sacc);
            sacc = fmaf(grow[q].y, wv.y, sacc);
            sacc = fmaf(grow[q].z, wv.z, sacc);
            sacc = fmaf(grow[q].w, wv.w, sacc);
        }
        o[jj] = sacc;
    }

    const int rg = row0 + wrow + rl;
    const int b  = rg >> 12;
    const int t  = rg & 4095;
    float* op = out + ((size_t)(kg * 4 + b) * 4096 + t) * 12;
    *(f32x4*)(op + 0) = {o[0], o[1], o[2],  o[3]};
    *(f32x4*)(op + 4) = {o[4], o[5], o[6],  o[7]};
    *(f32x4*)(op + 8) = {o[8], o[9], o[10], o[11]};
}

extern "C" void kernel_launch(void* const* d_in, const int* in_sizes, int n_in,
                              void* d_out, int out_size, void* d_ws, size_t ws_size,
                              hipStream_t stream) {
    const float* x  = (const float*)d_in[0];
    const float* W1 = (const float*)d_in[1];
    const float* W2 = (const float*)d_in[2];
    float* out = (float*)d_out;
    ushort* w1b = (ushort*)d_ws;

    w1cvt_kernel<<<(LTOT * DDIM) / 256, 256, 0, stream>>>(W1, w1b);
    fused_kernel<<<16384 / 64, 256, 0, stream>>>(x, w1b, W2, out);
}

// Round 6
// 76.948 us; speedup vs baseline: 1.1793x; 1.1793x over previous
//
#include <hip/hip_runtime.h>
#include <hip/hip_bf16.h>

// x: [4, 4096, 4096] f32, W1: [48, 4096] f32, W2: [48, 48] f32
// out: [4, 4, 4096, 12] f32  (C, B, T, L/C)
#define DDIM 4096
#define LTOT 48

typedef __attribute__((ext_vector_type(4))) float f32x4;
typedef __attribute__((ext_vector_type(8))) short bf16x8;

__device__ __forceinline__ unsigned cvt_pk(float x, float y) {
    union { __hip_bfloat162 h; unsigned u; } c;
    c.h = __float22bfloat162_rn(make_float2(x, y));
    return c.u;
}

// ---- kernel 0: W1 fp32 -> bf16 (RNE) into workspace ----
__global__ void w1cvt_kernel(const float* __restrict__ w1, ushort* __restrict__ w1b) {
    int i = blockIdx.x * 256 + threadIdx.x;
    union { float f; unsigned u; } v; v.f = w1[i];
    unsigned r = v.u + 0x7fffu + ((v.u >> 16) & 1u);
    w1b[i] = (ushort)(r >> 16);
}

// ---- fused: reg-staged linear streaming (global->reg->LDS), 4-wave K-split,
//      16-row blocks, single wave-private LDS buffer, MFMA + epilogue ----
__global__ __launch_bounds__(256, 4) void fused_kernel(
        const float* __restrict__ x,
        const ushort* __restrict__ w1b,
        const float* __restrict__ w2,
        float* __restrict__ out) {
    // [0,16384): 4 waves x 4KB staging. Epilogue overlays after syncthreads.
    __shared__ __align__(16) char smem[25600];

    const int tid  = threadIdx.x;
    const int wave = tid >> 6;
    const int lane = tid & 63;
    const int rl   = lane & 15;   // A-row / B-row / C-col
    const int kg   = lane >> 4;   // k-group 0..3 (also staging row-in-group)
    const int sblk = lane & 15;   // staging 16B-block within row
    const int row0 = blockIdx.x * 16;
    const int kw   = wave * 1024; // per-wave K range

    char* sbuf = smem + wave * 4096;   // wave-private buffer: 16 rows x 256B

    const float*  xs = x   + (size_t)row0 * DDIM + kw;
    const ushort* bp = w1b + (size_t)rl * DDIM + kw + kg * 8;

    // ds_write offsets: instr j covers rows 4j..4j+3 (lane -> row 4j+kg, block sblk)
    int dwo[4];
    #pragma unroll
    for (int j = 0; j < 4; ++j) {
        int r = 4 * j + kg;
        dwo[j] = r * 256 + ((sblk ^ r) & 15) * 16;
    }
    // ds_read frag offsets: (K-step t, piece p) -> logical block t*8+kg*2+p
    int dro[2][2];
    #pragma unroll
    for (int t = 0; t < 2; ++t)
        #pragma unroll
        for (int p = 0; p < 2; ++p) {
            int b = t * 8 + kg * 2 + p;
            dro[t][p] = rl * 256 + ((b ^ rl) & 15) * 16;
        }

    f32x4 S[4];   // stage registers (chunk in flight)
    auto stageLoad = [&](int c) {
        #pragma unroll
        for (int j = 0; j < 4; ++j)
            S[j] = __builtin_nontemporal_load(
                (const f32x4*)(xs + (size_t)(4 * j + kg) * DDIM + c * 64 + sblk * 4));
    };
    auto stageWrite = [&]() {
        #pragma unroll
        for (int j = 0; j < 4; ++j)
            *(f32x4*)(sbuf + dwo[j]) = S[j];
    };

    f32x4 acc[3] = {{0.f,0.f,0.f,0.f},{0.f,0.f,0.f,0.f},{0.f,0.f,0.f,0.f}};
    float ss = 0.f;

    stageLoad(0);
    stageWrite();

    #pragma unroll 2
    for (int c = 0; c < 16; ++c) {
        // B fragments for this chunk (2 K-steps x 3 n-tiles), issued FIRST so
        // their vmcnt waits never force the newer stage loads to retire.
        bf16x8 Bf[2][3];
        #pragma unroll
        for (int t = 0; t < 2; ++t)
            #pragma unroll
            for (int n = 0; n < 3; ++n)
                Bf[t][n] = *(const bf16x8*)(bp + c * 64 + t * 32 + n * 16 * DDIM);
        __builtin_amdgcn_sched_barrier(0);
        if (c < 15) stageLoad(c + 1);          // next chunk -> regs (in flight)
        __builtin_amdgcn_sched_barrier(0);

        // fragments of chunk c from LDS (floor-rate swizzled b128 reads)
        f32x4 A[2][2];
        #pragma unroll
        for (int t = 0; t < 2; ++t)
            #pragma unroll
            for (int p = 0; p < 2; ++p)
                A[t][p] = *(const f32x4*)(sbuf + dro[t][p]);

        #pragma unroll
        for (int t = 0; t < 2; ++t) {
            f32x4 a0 = A[t][0], a1 = A[t][1];
            ss = fmaf(a0.x, a0.x, ss); ss = fmaf(a0.y, a0.y, ss);
            ss = fmaf(a0.z, a0.z, ss); ss = fmaf(a0.w, a0.w, ss);
            ss = fmaf(a1.x, a1.x, ss); ss = fmaf(a1.y, a1.y, ss);
            ss = fmaf(a1.z, a1.z, ss); ss = fmaf(a1.w, a1.w, ss);
            union { bf16x8 v; unsigned u[4]; } af;
            af.u[0] = cvt_pk(a0.x, a0.y); af.u[1] = cvt_pk(a0.z, a0.w);
            af.u[2] = cvt_pk(a1.x, a1.y); af.u[3] = cvt_pk(a1.z, a1.w);
            #pragma unroll
            for (int n = 0; n < 3; ++n)
                acc[n] = __builtin_amdgcn_mfma_f32_16x16x32_bf16(
                             af.v, Bf[t][n], acc[n], 0, 0, 0);
        }
        // write next chunk into the (now-consumed) buffer; DS ops are in-order
        // per wave, so this cannot pass the frag reads above.
        if (c < 15) stageWrite();
    }

    // ---- reductions & epilogue (R2/R4-proven) ----
    ss += __shfl_xor(ss, 16);
    ss += __shfl_xor(ss, 32);
    __syncthreads();   // staging done everywhere -> overlay LDS

    float* dots = (float*)smem;             // [4][16][48] = 12288 B
    float* ssw  = (float*)(smem + 12288);   // [4][16]     =   256 B
    float* scl  = (float*)(smem + 12544);   // [16]        =    64 B
    float* gbuf = (float*)(smem + 12608);   // [16][48]    =  3072 B
    float* w2s  = (float*)(smem + 15680);   // [48][48]    =  9216 B

    if (lane < 16) ssw[wave * 16 + lane] = ss;

    #pragma unroll
    for (int n = 0; n < 3; ++n)
        #pragma unroll
        for (int i = 0; i < 4; ++i)
            dots[(wave * 16 + kg * 4 + i) * 48 + n * 16 + rl] = acc[n][i];

    for (int i = tid; i < LTOT * LTOT; i += 256) w2s[i] = w2[i];
    __syncthreads();

    if (tid < 16) {
        float st = ssw[0 * 16 + tid] + ssw[1 * 16 + tid]
                 + ssw[2 * 16 + tid] + ssw[3 * 16 + tid];
        scl[tid] = rsqrtf(st * (1.0f / (float)DDIM) + 1e-5f);
    }
    __syncthreads();

    #pragma unroll
    for (int i = 0; i < 3; ++i) {
        int v = tid + i * 256;
        int row = v / 48, col = v - row * 48;
        float d = dots[(0 * 16 + row) * 48 + col] + dots[(1 * 16 + row) * 48 + col]
                + dots[(2 * 16 + row) * 48 + col] + dots[(3 * 16 + row) * 48 + col];
        float h = d * scl[row];
        gbuf[row * 48 + col] = h * 0.5f * (1.0f + erff(h * 0.70710678118654752f));
    }
    __syncthreads();

    #pragma unroll
    for (int i = 0; i < 3; ++i) {
        int v = tid + i * 256;
        int row = v / 48, l = v - row * 48;
        float sacc = 0.f;
        #pragma unroll
        for (int k = 0; k < LTOT; ++k)
            sacc = fmaf(gbuf[row * 48 + k], w2s[l * LTOT + k], sacc);
        int rg = row0 + row;
        int b  = rg >> 12;
        int t  = rg & 4095;
        int cc = l / 12, j = l - cc * 12;
        out[(((size_t)(cc * 4 + b) * 4096 + t) * 12) + j] = sacc;
    }
}

extern "C" void kernel_launch(void* const* d_in, const int* in_sizes, int n_in,
                              void* d_out, int out_size, void* d_ws, size_t ws_size,
                              hipStream_t stream) {
    const float* x  = (const float*)d_in[0];
    const float* W1 = (const float*)d_in[1];
    const float* W2 = (const float*)d_in[2];
    float* out = (float*)d_out;
    ushort* w1b = (ushort*)d_ws;

    w1cvt_kernel<<<(LTOT * DDIM) / 256, 256, 0, stream>>>(W1, w1b);
    fused_kernel<<<16384 / 16, 256, 0, stream>>>(x, w1b, W2, out);
}